// Round 5
// baseline (602.774 us; speedup 1.0000x reference)
//
#include <hip/hip_runtime.h>

typedef __bf16 bf16x8 __attribute__((ext_vector_type(8)));
typedef float f32x4 __attribute__((ext_vector_type(4)));

#define AS1 __attribute__((address_space(1)))
#define AS3 __attribute__((address_space(3)))

__device__ __forceinline__ unsigned short f2bf(float f) {
    unsigned int u = __builtin_bit_cast(unsigned int, f);
    u += 0x7fffu + ((u >> 16) & 1u);
    return (unsigned short)(u >> 16);
}
__device__ __forceinline__ float bf2f(unsigned short u) {
    return __builtin_bit_cast(float, (unsigned)u << 16);
}

// XOR swizzle for 1024B-row LDS tiles: byte ^= ((row&7)<<4)
__device__ __forceinline__ unsigned swz1k(unsigned byte) {
    return byte ^ ((byte >> 6) & 0x70u);
}

// Raw barrier: LDS-visibility only; does NOT drain vmcnt, so in-flight
// global_load_lds prefetches ride across it.
__device__ __forceinline__ void bar_lgkm() {
    asm volatile("s_waitcnt lgkmcnt(0)\n\ts_barrier" ::: "memory");
}

// async global->LDS, 16B per lane. lptr must be wave-uniform (HW adds lane*16).
__device__ __forceinline__ void gll16(const void* g, void* l) {
    __builtin_amdgcn_global_load_lds((const AS1 void*)g, (AS3 void*)l, 16, 0, 0);
}

// ---------------- K1: Pc[kc][j][t] = M[kc*32+t][j], M = Wq^T Wk  (bf16)
// plus Wv -> bf16 copy.
__global__ __launch_bounds__(256) void prep_kernel(
    const float* __restrict__ Wq, const float* __restrict__ Wk,
    const float* __restrict__ Wv, unsigned short* __restrict__ Pc,
    unsigned short* __restrict__ Wvb)
{
    int b = blockIdx.x;
    if (b < 1024) {
        int j0 = (b >> 4) * 8;
        int kc = b & 15;
        int jloc = threadIdx.x >> 5;
        int t = threadIdx.x & 31;
        int j = j0 + jloc, d = kc * 32 + t;
        float acc = 0.f;
        #pragma unroll 8
        for (int e = 0; e < 512; ++e)
            acc = fmaf(Wk[e * 512 + j], Wq[e * 512 + d], acc);
        Pc[((kc * 512) + j) * 32 + t] = f2bf(acc);
    } else {
        int i = (b - 1024) * 256 + (int)threadIdx.x;
        Wvb[i] = f2bf(Wv[i]);
    }
}

// ---------------- K2: persistent fused kernel. Grid 256 (1 block/CU),
// 16 tiles of 32 rows (2 batches) per block. Next tile's H prefetched via
// global_load_lds into a 64KB fp32 LDS ring (zero VGPR cost, rides across
// the raw mid-tile barriers; drained for free at the next tile-top sync).
__global__ __launch_bounds__(512, 2) void attn_main_kernel(
    const float* __restrict__ H, const float* __restrict__ F,
    const unsigned short* __restrict__ Pc,
    float* __restrict__ out, unsigned short* __restrict__ g_ws)
{
    extern __shared__ char smem[];
    char* HBF  = smem;                        // 32 rows x 1024B bf16, swizzled (32 KB)
    char* TBF  = smem + 32768;                // 32 KB
    char* HL0  = smem + 65536;                // 16 rows x 2048B fp32 (32 KB)
    char* HL1  = smem + 98304;                // 32 KB
    float* wbuf = (float*)(smem + 131072);    // [2][16] = 128 B
    float* FL   = (float*)(smem + 131200);    // 512 raw F
    float* LFL  = (float*)(smem + 133248);    // 512 log(F+eps)

    const int tid = threadIdx.x;
    const int wv = tid >> 6;
    const int ln = tid & 63;
    const int rl = ln & 15;   // fragment row/col within tile
    const int kg = ln >> 4;   // k-group 0..3

    const int T = 16;
    const long long tile0 = (long long)blockIdx.x * T;

    // ---- stage F + log(F+eps) for the whole block (32 batches = 512 floats)
    {
        float fv = F[tile0 * 32 + tid];
        FL[tid] = fv;
        LFL[tid] = logf(fv + 1e-8f);
    }

    // B-fragment base: Pc[((kc*512 + j)*32 + kg*8)], j = wv*64+jj*16+rl
    const unsigned short* bptr = Pc + ((wv * 64 + rl) * 32 + kg * 8);

    // ---- prologue: prefetch tile 0 (two 16-row halves -> HL0/HL1)
    {
        const char* hbase = (const char*)(H + tile0 * 32 * 512);
        #pragma unroll
        for (int i = 0; i < 4; ++i) {
            gll16(hbase + wv * 4096 + i * 1024 + ln * 16, HL0 + wv * 4096 + i * 1024);
            gll16(hbase + 32768 + wv * 4096 + i * 1024 + ln * 16, HL1 + wv * 4096 + i * 1024);
        }
    }

    for (int t = 0; t < T; ++t) {
        const long long gb0 = (tile0 + t) * 2;   // first batch idx of this tile
        const int t32 = t * 32;

        // tile-top: full sync. Drains vmcnt, but the glls were issued a full
        // tile ago (steady state) so this is cheap. Also WAR-protects HBF
        // (phase 4 readers of tile t-1) and the HL slots.
        __syncthreads();

        // ---- convert staged fp32 -> bf16 swizzled HBF
        #pragma unroll
        for (int q = 0; q < 4; ++q) {
            int idx = q * 512 + tid;              // float4 idx in [0,2048)
            float4 v = *(const float4*)(HL0 + idx * 16);
            ushort4 bv;
            bv.x = f2bf(v.x); bv.y = f2bf(v.y); bv.z = f2bf(v.z); bv.w = f2bf(v.w);
            unsigned row = (unsigned)(idx >> 7), c4 = (unsigned)(idx & 127);
            *(ushort4*)(HBF + swz1k(row * 1024u + c4 * 8u)) = bv;
        }
        #pragma unroll
        for (int q = 0; q < 4; ++q) {
            int idx = q * 512 + tid;
            float4 v = *(const float4*)(HL1 + idx * 16);
            ushort4 bv;
            bv.x = f2bf(v.x); bv.y = f2bf(v.y); bv.z = f2bf(v.z); bv.w = f2bf(v.w);
            unsigned row = (unsigned)(16 + (idx >> 7)), c4 = (unsigned)(idx & 127);
            *(ushort4*)(HBF + swz1k(row * 1024u + c4 * 8u)) = bv;
        }

        bar_lgkm();   // HBF ready; HL slots fully consumed

        // ---- issue next tile's H prefetch (rides across everything below)
        if (t + 1 < T) {
            const char* hbase = (const char*)(H + (tile0 + t + 1) * 32 * 512);
            #pragma unroll
            for (int i = 0; i < 4; ++i) {
                gll16(hbase + wv * 4096 + i * 1024 + ln * 16, HL0 + wv * 4096 + i * 1024);
                gll16(hbase + 32768 + wv * 4096 + i * 1024 + ln * 16, HL1 + wv * 4096 + i * 1024);
            }
        }

        // ---- GEMM: T = Hbf @ M, 2-deep Pc prefetch, no barriers
        f32x4 acc[2][4];
        #pragma unroll
        for (int i = 0; i < 2; ++i)
            #pragma unroll
            for (int jj = 0; jj < 4; ++jj)
                acc[i][jj] = f32x4{0.f, 0.f, 0.f, 0.f};

        bf16x8 b0[4], b1[4];
        #pragma unroll
        for (int jj = 0; jj < 4; ++jj) b0[jj] = *(const bf16x8*)(bptr + jj * 512);
        #pragma unroll
        for (int jj = 0; jj < 4; ++jj) b1[jj] = *(const bf16x8*)(bptr + 16384 + jj * 512);

        #pragma unroll
        for (int kc = 0; kc < 16; ++kc) {
            bf16x8 bn[4];
            if (kc < 14) {
                #pragma unroll
                for (int jj = 0; jj < 4; ++jj)
                    bn[jj] = *(const bf16x8*)(bptr + (kc + 2) * 16384 + jj * 512);
            }
            bf16x8 a[2];
            #pragma unroll
            for (int i = 0; i < 2; ++i) {
                unsigned off = (unsigned)(i * 16 + rl) * 1024u + (unsigned)kc * 64u + (unsigned)kg * 16u;
                a[i] = *(bf16x8*)(HBF + swz1k(off));
            }
            #pragma unroll
            for (int i = 0; i < 2; ++i)
                #pragma unroll
                for (int jj = 0; jj < 4; ++jj)
                    acc[i][jj] = __builtin_amdgcn_mfma_f32_16x16x32_bf16(a[i], b0[jj], acc[i][jj], 0, 0, 0);
            #pragma unroll
            for (int jj = 0; jj < 4; ++jj) { b0[jj] = b1[jj]; b1[jj] = bn[jj]; }
        }

        // write T into TBF (C layout: col=lane&15, row=(lane>>4)*4+p)
        #pragma unroll
        for (int i = 0; i < 2; ++i)
            #pragma unroll
            for (int jj = 0; jj < 4; ++jj)
                #pragma unroll
                for (int p = 0; p < 4; ++p) {
                    unsigned row = (unsigned)(i * 16 + kg * 4 + p);
                    unsigned col = (unsigned)(wv * 64 + jj * 16 + rl);
                    *(unsigned short*)(TBF + swz1k(row * 1024u + col * 2u)) = f2bf(acc[i][jj][p]);
                }

        bar_lgkm();   // TBF ready

        // ---- phase 3: waves 0-1 scores+softmax+w ; waves 2-5 residual pool
        if (wv < 2) {
            f32x4 sc = f32x4{0.f, 0.f, 0.f, 0.f};
            #pragma unroll
            for (int kc = 0; kc < 16; ++kc) {
                unsigned off = (unsigned)(wv * 16 + rl) * 1024u + (unsigned)kc * 64u + (unsigned)kg * 16u;
                bf16x8 aT = *(bf16x8*)(TBF + swz1k(off));
                bf16x8 bH = *(bf16x8*)(HBF + swz1k(off));   // H rows as B == H^T
                sc = __builtin_amdgcn_mfma_f32_16x16x32_bf16(aT, bH, sc, 0, 0, 0);
            }
            float bias = LFL[t32 + wv * 16 + rl];           // log(F+eps) for key rl
            float alpha[4];
            #pragma unroll
            for (int p = 0; p < 4; ++p) {
                float s = sc[p] * 0.044194173824159216f + bias;  // 1/sqrt(512)
                float m = s;
                m = fmaxf(m, __shfl_xor(m, 8));
                m = fmaxf(m, __shfl_xor(m, 4));
                m = fmaxf(m, __shfl_xor(m, 2));
                m = fmaxf(m, __shfl_xor(m, 1));
                float e = expf(s - m);
                float sum = e;
                sum += __shfl_xor(sum, 8);
                sum += __shfl_xor(sum, 4);
                sum += __shfl_xor(sum, 2);
                sum += __shfl_xor(sum, 1);
                alpha[p] = e / sum;
            }
            float part = 0.f;
            #pragma unroll
            for (int p = 0; p < 4; ++p) part += FL[t32 + wv * 16 + kg * 4 + p] * alpha[p];
            part += __shfl_xor(part, 16);
            part += __shfl_xor(part, 32);
            if (ln < 16) wbuf[wv * 16 + ln] = part;
        } else if (wv < 6) {
            // residual F-pool: unit = (batch bb, d-half dh); lane covers 4 d-elems
            int u = wv - 2;
            int bb = u >> 1, dh = u & 1;
            const long long Bg = gb0 + bb;
            int d0 = dh * 256 + ln * 4;
            float o[4];
            #pragma unroll
            for (int q = 0; q < 4; ++q) o[q] = 0.f;
            #pragma unroll
            for (int k = 0; k < 16; ++k) {
                unsigned off = (unsigned)(bb * 16 + k) * 1024u + (unsigned)d0 * 2u;
                ushort4 h = *(ushort4*)(HBF + swz1k(off));
                float fk = FL[t32 + bb * 16 + k];
                o[0] = fmaf(fk, bf2f(h.x), o[0]); o[1] = fmaf(fk, bf2f(h.y), o[1]);
                o[2] = fmaf(fk, bf2f(h.z), o[2]); o[3] = fmaf(fk, bf2f(h.w), o[3]);
            }
            float4 oa; oa.x = o[0]; oa.y = o[1]; oa.z = o[2]; oa.w = o[3];
            *(float4*)(out + Bg * 512 + d0) = oa;
        }

        bar_lgkm();   // wbuf ready

        // ---- phase 4: g (bf16). 8 waves = 2 batches x 4 d-quarters, from LDS.
        {
            int bb = wv >> 2, q4 = wv & 3;
            const long long Bg = gb0 + bb;
            int d0 = q4 * 128 + ln * 2;
            float g0 = 0.f, g1 = 0.f;
            #pragma unroll
            for (int k = 0; k < 16; ++k) {
                unsigned off = (unsigned)(bb * 16 + k) * 1024u + (unsigned)d0 * 2u;
                ushort2 h = *(ushort2*)(HBF + swz1k(off));
                float wk = wbuf[bb * 16 + k];
                g0 = fmaf(wk, bf2f(h.x), g0); g1 = fmaf(wk, bf2f(h.y), g1);
            }
            ushort2 g2; g2.x = f2bf(g0); g2.y = f2bf(g1);
            *(ushort2*)(g_ws + Bg * 512 + d0) = g2;
        }
    }
}

// ---------------- K3: out += g @ Wv^T   (8192x512 @ 512x512, bf16 MFMA)
__global__ __launch_bounds__(256) void out_gemm_kernel(
    const unsigned short* __restrict__ g_ws,
    const unsigned short* __restrict__ Wvb,
    float* __restrict__ out)
{
    extern __shared__ char smem[];  // 32 KB: 32 rows x 1024B, swizzled
    const int tid = threadIdx.x;
    const int wv = tid >> 6, ln = tid & 63;
    const int rl = ln & 15, kg = ln >> 4;
    const long long r0 = (long long)blockIdx.x * 32;
    {
        const uint4* src = (const uint4*)(g_ws + r0 * 512);
        #pragma unroll
        for (int q = 0; q < 8; ++q) {
            int idx = q * 256 + tid;
            *(uint4*)(smem + swz1k((unsigned)idx * 16u)) = src[idx];
        }
    }
    __syncthreads();
    f32x4 acc[2][8];
    #pragma unroll
    for (int i = 0; i < 2; ++i)
        #pragma unroll
        for (int jj = 0; jj < 8; ++jj)
            acc[i][jj] = f32x4{0.f, 0.f, 0.f, 0.f};
    for (int kc = 0; kc < 16; ++kc) {
        bf16x8 a[2];
        #pragma unroll
        for (int i = 0; i < 2; ++i) {
            unsigned off = (unsigned)(i * 16 + rl) * 1024u + (unsigned)kc * 64u + (unsigned)kg * 16u;
            a[i] = *(bf16x8*)(smem + swz1k(off));
        }
        bf16x8 bfr[8];
        #pragma unroll
        for (int jj = 0; jj < 8; ++jj) {
            int n = wv * 128 + jj * 16 + rl;
            bfr[jj] = *(const bf16x8*)(Wvb + n * 512 + kc * 32 + kg * 8);  // Wv[n][k] row-major
        }
        #pragma unroll
        for (int i = 0; i < 2; ++i)
            #pragma unroll
            for (int jj = 0; jj < 8; ++jj)
                acc[i][jj] = __builtin_amdgcn_mfma_f32_16x16x32_bf16(a[i], bfr[jj], acc[i][jj], 0, 0, 0);
    }
    #pragma unroll
    for (int i = 0; i < 2; ++i)
        #pragma unroll
        for (int jj = 0; jj < 8; ++jj)
            #pragma unroll
            for (int p = 0; p < 4; ++p) {
                int row = i * 16 + kg * 4 + p;
                int col = wv * 128 + jj * 16 + rl;
                out[(r0 + row) * 512 + col] += acc[i][jj][p];
            }
}

extern "C" void kernel_launch(void* const* d_in, const int* in_sizes, int n_in,
                              void* d_out, int out_size, void* d_ws, size_t ws_size,
                              hipStream_t stream)
{
    const float* H  = (const float*)d_in[0];
    const float* F  = (const float*)d_in[1];
    const float* Wq = (const float*)d_in[2];
    const float* Wk = (const float*)d_in[3];
    const float* Wv = (const float*)d_in[4];
    float* out = (float*)d_out;

    unsigned short* Pc  = (unsigned short*)d_ws;       // 16*512*32   = 262144 bf16
    unsigned short* Wvb = Pc + 262144;                 // 512*512     = 262144 bf16
    unsigned short* g   = Wvb + 262144;                // 8192*512    = 4194304 bf16
    (void)in_sizes; (void)n_in; (void)out_size; (void)ws_size;

    hipLaunchKernelGGL(prep_kernel, dim3(2048), dim3(256), 0, stream, Wq, Wk, Wv, Pc, Wvb);
    hipLaunchKernelGGL(attn_main_kernel, dim3(256), dim3(512), 135296, stream, H, F, Pc, out, g);
    hipLaunchKernelGGL(out_gemm_kernel, dim3(256), dim3(256), 32768, stream, g, Wvb, out);
}

// Round 6
// 209.713 us; speedup vs baseline: 2.8743x; 2.8743x over previous
//
#include <hip/hip_runtime.h>

typedef __bf16 bf16x8 __attribute__((ext_vector_type(8)));
typedef float f32x4 __attribute__((ext_vector_type(4)));

__device__ __forceinline__ unsigned short f2bf(float f) {
    unsigned int u = __builtin_bit_cast(unsigned int, f);
    u += 0x7fffu + ((u >> 16) & 1u);
    return (unsigned short)(u >> 16);
}
__device__ __forceinline__ float bf2f(unsigned short u) {
    return __builtin_bit_cast(float, (unsigned)u << 16);
}

// XOR swizzle for 1024B-row LDS tiles: byte ^= ((row&7)<<4)
__device__ __forceinline__ unsigned swz1k(unsigned byte) {
    return byte ^ ((byte >> 6) & 0x70u);
}

// Raw barrier: LDS-visibility only; does NOT drain vmcnt. All global loads in
// this kernel are register-consumed (counted vmcnt at use), so no drain needed.
__device__ __forceinline__ void bar_lgkm() {
    asm volatile("s_waitcnt lgkmcnt(0)\n\ts_barrier" ::: "memory");
}

// ---------------- K1: Pc[kc][j][t] = M[kc*32+t][j], M = Wq^T Wk  (bf16)
// plus Wv -> bf16 copy.
__global__ __launch_bounds__(256) void prep_kernel(
    const float* __restrict__ Wq, const float* __restrict__ Wk,
    const float* __restrict__ Wv, unsigned short* __restrict__ Pc,
    unsigned short* __restrict__ Wvb)
{
    int b = blockIdx.x;
    if (b < 1024) {
        int j0 = (b >> 4) * 8;
        int kc = b & 15;
        int jloc = threadIdx.x >> 5;
        int t = threadIdx.x & 31;
        int j = j0 + jloc, d = kc * 32 + t;
        float acc = 0.f;
        #pragma unroll 8
        for (int e = 0; e < 512; ++e)
            acc = fmaf(Wk[e * 512 + j], Wq[e * 512 + d], acc);
        Pc[((kc * 512) + j) * 32 + t] = f2bf(acc);
    } else {
        int i = (b - 1024) * 256 + (int)threadIdx.x;
        Wvb[i] = f2bf(Wv[i]);
    }
}

// ---------------- K2: fused main kernel. 1 block = 4 batches = 64 H rows.
// H loaded column-half-first (16 float4/thread issued up-front); GEMM kc 0..7
// runs on half-0 while half-1 arrives; 3-deep Pc register prefetch; raw
// lgkm-only barriers (no vmcnt drains).
__global__ __launch_bounds__(512, 1) void attn_main_kernel(
    const float* __restrict__ H, const float* __restrict__ F,
    const unsigned short* __restrict__ Pc,
    float* __restrict__ out, unsigned short* __restrict__ g_ws)
{
    extern __shared__ char smem[];
    char* HBF = smem;                        // 64 rows x 1024B, swizzled (64 KB)
    char* TBF = smem + 65536;                // 64 rows x 1024B, swizzled (64 KB)
    float* wbuf = (float*)(smem + 131072);   // [4][16]
    float* FL   = (float*)(smem + 131328);   // [64] F values for 4 batches
    float* LFL  = (float*)(smem + 131584);   // [64] log(F+eps)

    const int tid = threadIdx.x;
    const int wv = tid >> 6;
    const int ln = tid & 63;
    const int rl = ln & 15;   // fragment row/col within tile
    const int kg = ln >> 4;   // k-group 0..3
    const long long gr0 = (long long)blockIdx.x * 64;

    // ---- stage F + log(F+eps) (64 floats); load issues before H-load wall
    float fval = 0.f;
    if (tid < 64) fval = F[blockIdx.x * 64 + tid];

    // ---- issue ALL 16 H loads, column-half-major:
    // rep 0..7  : rows 0..63, cols 0..255   (row = rep*8+wv, c4 = ln)
    // rep 8..15 : rows 0..63, cols 256..511 (row = (rep-8)*8+wv, c4 = 64+ln)
    const float4* src = (const float4*)(H + gr0 * 512);
    float4 hreg[16];
    #pragma unroll
    for (int rep = 0; rep < 8; ++rep)
        hreg[rep] = src[(rep * 8 + wv) * 128 + ln];
    #pragma unroll
    for (int rep = 0; rep < 8; ++rep)
        hreg[8 + rep] = src[(rep * 8 + wv) * 128 + 64 + ln];

    if (tid < 64) {
        FL[tid] = fval;
        LFL[tid] = logf(fval + 1e-8f);
    }

    // ---- convert half-0 (cols 0..255) -> HBF
    #pragma unroll
    for (int rep = 0; rep < 8; ++rep) {
        ushort4 bv;
        bv.x = f2bf(hreg[rep].x); bv.y = f2bf(hreg[rep].y);
        bv.z = f2bf(hreg[rep].z); bv.w = f2bf(hreg[rep].w);
        unsigned byte = (unsigned)(rep * 8 + wv) * 1024u + (unsigned)ln * 8u;
        *(ushort4*)(HBF + swz1k(byte)) = bv;
    }

    // B-fragment base: Pc[((kc*512 + j)*32 + kg*8)], j = wv*64+jj*16+rl
    const unsigned short* bptr = Pc + ((wv * 64 + rl) * 32 + kg * 8);

    // ---- prime 3-deep Pc prefetch (kc = 0,1,2)
    bf16x8 st0[4], st1[4], st2[4];
    #pragma unroll
    for (int jj = 0; jj < 4; ++jj) st0[jj] = *(const bf16x8*)(bptr + 0 * 16384 + jj * 512);
    #pragma unroll
    for (int jj = 0; jj < 4; ++jj) st1[jj] = *(const bf16x8*)(bptr + 1 * 16384 + jj * 512);
    #pragma unroll
    for (int jj = 0; jj < 4; ++jj) st2[jj] = *(const bf16x8*)(bptr + 2 * 16384 + jj * 512);

    f32x4 acc[4][4];
    #pragma unroll
    for (int i = 0; i < 4; ++i)
        #pragma unroll
        for (int jj = 0; jj < 4; ++jj)
            acc[i][jj] = f32x4{0.f, 0.f, 0.f, 0.f};

    bar_lgkm();   // HBF half-0 + FL/LFL visible

    // ---- GEMM half-0: kc 0..7 (cols 0..255) while H half-1 arrives
    #pragma unroll
    for (int kc = 0; kc < 8; ++kc) {
        bf16x8 bn[4];
        #pragma unroll
        for (int jj = 0; jj < 4; ++jj)
            bn[jj] = *(const bf16x8*)(bptr + (kc + 3) * 16384 + jj * 512);
        bf16x8 a[4];
        #pragma unroll
        for (int i = 0; i < 4; ++i) {
            unsigned off = (unsigned)(i * 16 + rl) * 1024u + (unsigned)kc * 64u + (unsigned)kg * 16u;
            a[i] = *(bf16x8*)(HBF + swz1k(off));
        }
        #pragma unroll
        for (int i = 0; i < 4; ++i)
            #pragma unroll
            for (int jj = 0; jj < 4; ++jj)
                acc[i][jj] = __builtin_amdgcn_mfma_f32_16x16x32_bf16(a[i], st0[jj], acc[i][jj], 0, 0, 0);
        #pragma unroll
        for (int jj = 0; jj < 4; ++jj) { st0[jj] = st1[jj]; st1[jj] = st2[jj]; st2[jj] = bn[jj]; }
    }

    // ---- convert half-1 (cols 256..511); loads landed during GEMM half-0
    #pragma unroll
    for (int rep = 0; rep < 8; ++rep) {
        ushort4 bv;
        bv.x = f2bf(hreg[8 + rep].x); bv.y = f2bf(hreg[8 + rep].y);
        bv.z = f2bf(hreg[8 + rep].z); bv.w = f2bf(hreg[8 + rep].w);
        unsigned byte = (unsigned)(rep * 8 + wv) * 1024u + (unsigned)(64 + ln) * 8u;
        *(ushort4*)(HBF + swz1k(byte)) = bv;
    }
    bar_lgkm();   // HBF half-1 visible

    // ---- GEMM half-1: kc 8..15
    #pragma unroll
    for (int kc = 8; kc < 16; ++kc) {
        bf16x8 bn[4];
        if (kc < 13) {
            #pragma unroll
            for (int jj = 0; jj < 4; ++jj)
                bn[jj] = *(const bf16x8*)(bptr + (kc + 3) * 16384 + jj * 512);
        }
        bf16x8 a[4];
        #pragma unroll
        for (int i = 0; i < 4; ++i) {
            unsigned off = (unsigned)(i * 16 + rl) * 1024u + (unsigned)kc * 64u + (unsigned)kg * 16u;
            a[i] = *(bf16x8*)(HBF + swz1k(off));
        }
        #pragma unroll
        for (int i = 0; i < 4; ++i)
            #pragma unroll
            for (int jj = 0; jj < 4; ++jj)
                acc[i][jj] = __builtin_amdgcn_mfma_f32_16x16x32_bf16(a[i], st0[jj], acc[i][jj], 0, 0, 0);
        #pragma unroll
        for (int jj = 0; jj < 4; ++jj) { st0[jj] = st1[jj]; st1[jj] = st2[jj]; st2[jj] = bn[jj]; }
    }

    // write T (bf16, swizzled rows) into TBF (C layout: row=kg*4+p, col=rl)
    #pragma unroll
    for (int i = 0; i < 4; ++i)
        #pragma unroll
        for (int jj = 0; jj < 4; ++jj)
            #pragma unroll
            for (int p = 0; p < 4; ++p) {
                unsigned row = (unsigned)(i * 16 + kg * 4 + p);
                unsigned col = (unsigned)(wv * 64 + jj * 16 + rl);
                *(unsigned short*)(TBF + swz1k(row * 1024u + col * 2u)) = f2bf(acc[i][jj][p]);
            }
    bar_lgkm();   // TBF ready

    // ---- phase 3: waves 0-3: scores+softmax+w ; waves 4-7: residual pool
    if (wv < 4) {
        f32x4 sc = f32x4{0.f, 0.f, 0.f, 0.f};
        #pragma unroll
        for (int kc = 0; kc < 16; ++kc) {
            unsigned off = (unsigned)(wv * 16 + rl) * 1024u + (unsigned)kc * 64u + (unsigned)kg * 16u;
            bf16x8 aT = *(bf16x8*)(TBF + swz1k(off));
            bf16x8 bH = *(bf16x8*)(HBF + swz1k(off));   // H rows as B == H^T
            sc = __builtin_amdgcn_mfma_f32_16x16x32_bf16(aT, bH, sc, 0, 0, 0);
        }
        float bias = LFL[wv * 16 + rl];                 // log(F+eps) for key col rl
        float alpha[4];
        #pragma unroll
        for (int p = 0; p < 4; ++p) {
            float s = sc[p] * 0.044194173824159216f + bias;  // 1/sqrt(512)
            float m = s;
            m = fmaxf(m, __shfl_xor(m, 8));
            m = fmaxf(m, __shfl_xor(m, 4));
            m = fmaxf(m, __shfl_xor(m, 2));
            m = fmaxf(m, __shfl_xor(m, 1));
            float e = expf(s - m);
            float sum = e;
            sum += __shfl_xor(sum, 8);
            sum += __shfl_xor(sum, 4);
            sum += __shfl_xor(sum, 2);
            sum += __shfl_xor(sum, 1);
            alpha[p] = e / sum;
        }
        float part = 0.f;
        #pragma unroll
        for (int p = 0; p < 4; ++p) part += FL[wv * 16 + kg * 4 + p] * alpha[p];
        part += __shfl_xor(part, 16);
        part += __shfl_xor(part, 32);
        if (ln < 16) wbuf[wv * 16 + ln] = part;
    } else {
        // residual F-pool: wave handles batch bb, lane covers 8 d-elems
        int bb = wv - 4;
        const long long Bg = (long long)blockIdx.x * 4 + bb;
        int d0 = ln * 8;
        float o[8];
        #pragma unroll
        for (int q = 0; q < 8; ++q) o[q] = 0.f;
        #pragma unroll
        for (int k = 0; k < 16; ++k) {
            unsigned off = (unsigned)(bb * 16 + k) * 1024u + (unsigned)d0 * 2u;
            ushort4 h0 = *(ushort4*)(HBF + swz1k(off));
            ushort4 h1 = *(ushort4*)(HBF + swz1k(off + 8u));
            float fk = FL[bb * 16 + k];
            o[0] = fmaf(fk, bf2f(h0.x), o[0]); o[1] = fmaf(fk, bf2f(h0.y), o[1]);
            o[2] = fmaf(fk, bf2f(h0.z), o[2]); o[3] = fmaf(fk, bf2f(h0.w), o[3]);
            o[4] = fmaf(fk, bf2f(h1.x), o[4]); o[5] = fmaf(fk, bf2f(h1.y), o[5]);
            o[6] = fmaf(fk, bf2f(h1.z), o[6]); o[7] = fmaf(fk, bf2f(h1.w), o[7]);
        }
        float4 oa; oa.x = o[0]; oa.y = o[1]; oa.z = o[2]; oa.w = o[3];
        float4 ob; ob.x = o[4]; ob.y = o[5]; ob.z = o[6]; ob.w = o[7];
        *(float4*)(out + Bg * 512 + d0) = oa;
        *(float4*)(out + Bg * 512 + d0 + 4) = ob;
    }
    bar_lgkm();   // wbuf ready

    // ---- phase 4: g (bf16). 8 waves = 4 batches x 2 d-halves, from LDS.
    {
        int bb = wv >> 1, dh = wv & 1;
        const long long Bg = (long long)blockIdx.x * 4 + bb;
        int d0 = dh * 256 + ln * 4;
        float g[4];
        #pragma unroll
        for (int q = 0; q < 4; ++q) g[q] = 0.f;
        #pragma unroll
        for (int k = 0; k < 16; ++k) {
            unsigned off = (unsigned)(bb * 16 + k) * 1024u + (unsigned)d0 * 2u;
            ushort4 h = *(ushort4*)(HBF + swz1k(off));
            float wk = wbuf[bb * 16 + k];
            g[0] = fmaf(wk, bf2f(h.x), g[0]); g[1] = fmaf(wk, bf2f(h.y), g[1]);
            g[2] = fmaf(wk, bf2f(h.z), g[2]); g[3] = fmaf(wk, bf2f(h.w), g[3]);
        }
        ushort4 g4; g4.x = f2bf(g[0]); g4.y = f2bf(g[1]); g4.z = f2bf(g[2]); g4.w = f2bf(g[3]);
        *(ushort4*)(g_ws + Bg * 512 + d0) = g4;
    }
}

// ---------------- K3: out += g @ Wv^T   (8192x512 @ 512x512, bf16 MFMA)
__global__ __launch_bounds__(256) void out_gemm_kernel(
    const unsigned short* __restrict__ g_ws,
    const unsigned short* __restrict__ Wvb,
    float* __restrict__ out)
{
    extern __shared__ char smem[];  // 32 KB: 32 rows x 1024B, swizzled
    const int tid = threadIdx.x;
    const int wv = tid >> 6, ln = tid & 63;
    const int rl = ln & 15, kg = ln >> 4;
    const long long r0 = (long long)blockIdx.x * 32;
    {
        const uint4* src = (const uint4*)(g_ws + r0 * 512);
        #pragma unroll
        for (int q = 0; q < 8; ++q) {
            int idx = q * 256 + tid;
            *(uint4*)(smem + swz1k((unsigned)idx * 16u)) = src[idx];
        }
    }
    __syncthreads();
    f32x4 acc[2][8];
    #pragma unroll
    for (int i = 0; i < 2; ++i)
        #pragma unroll
        for (int jj = 0; jj < 8; ++jj)
            acc[i][jj] = f32x4{0.f, 0.f, 0.f, 0.f};
    for (int kc = 0; kc < 16; ++kc) {
        bf16x8 a[2];
        #pragma unroll
        for (int i = 0; i < 2; ++i) {
            unsigned off = (unsigned)(i * 16 + rl) * 1024u + (unsigned)kc * 64u + (unsigned)kg * 16u;
            a[i] = *(bf16x8*)(smem + swz1k(off));
        }
        bf16x8 bfr[8];
        #pragma unroll
        for (int jj = 0; jj < 8; ++jj) {
            int n = wv * 128 + jj * 16 + rl;
            bfr[jj] = *(const bf16x8*)(Wvb + n * 512 + kc * 32 + kg * 8);  // Wv[n][k] row-major
        }
        #pragma unroll
        for (int i = 0; i < 2; ++i)
            #pragma unroll
            for (int jj = 0; jj < 8; ++jj)
                acc[i][jj] = __builtin_amdgcn_mfma_f32_16x16x32_bf16(a[i], bfr[jj], acc[i][jj], 0, 0, 0);
    }
    #pragma unroll
    for (int i = 0; i < 2; ++i)
        #pragma unroll
        for (int jj = 0; jj < 8; ++jj)
            #pragma unroll
            for (int p = 0; p < 4; ++p) {
                int row = i * 16 + kg * 4 + p;
                int col = wv * 128 + jj * 16 + rl;
                out[(r0 + row) * 512 + col] += acc[i][jj][p];
            }
}

extern "C" void kernel_launch(void* const* d_in, const int* in_sizes, int n_in,
                              void* d_out, int out_size, void* d_ws, size_t ws_size,
                              hipStream_t stream)
{
    const float* H  = (const float*)d_in[0];
    const float* F  = (const float*)d_in[1];
    const float* Wq = (const float*)d_in[2];
    const float* Wk = (const float*)d_in[3];
    const float* Wv = (const float*)d_in[4];
    float* out = (float*)d_out;

    unsigned short* Pc  = (unsigned short*)d_ws;       // 16*512*32   = 262144 bf16
    unsigned short* Wvb = Pc + 262144;                 // 512*512     = 262144 bf16
    unsigned short* g   = Wvb + 262144;                // 8192*512    = 4194304 bf16
    (void)in_sizes; (void)n_in; (void)out_size; (void)ws_size;

    hipLaunchKernelGGL(prep_kernel, dim3(2048), dim3(256), 0, stream, Wq, Wk, Wv, Pc, Wvb);
    hipLaunchKernelGGL(attn_main_kernel, dim3(2048), dim3(512), 131840, stream, H, F, Pc, out, g);
    hipLaunchKernelGGL(out_gemm_kernel, dim3(256), dim3(256), 32768, stream, g, Wvb, out);
}